// Round 7
// baseline (74.590 us; speedup 1.0000x reference)
//
#include <hip/hip_runtime.h>
#include <math.h>

// Problem constants (from reference)
#define FH 64    // feature map H (axis indexed by x)
#define FW 64    // feature map W (axis indexed by y)
#define FC 256   // channels
#define PP 7     // pool output dim
#define NROI 256
#define CHMAX 16

#define MAPF4 (FH * FW * (FC / 4))           // 262144 float4 per map
#define WS_NEED ((size_t)3 * MAPF4 * 16)     // 12.58 MB: mpx, mpy, mpxy

__device__ __forceinline__ float4 fmax4(float4 a, float4 b) {
    return make_float4(fmaxf(a.x, b.x), fmaxf(a.y, b.y),
                       fmaxf(a.z, b.z), fmaxf(a.w, b.w));
}

// ---------------------------------------------------------------------------
// Build pass: stride-1 separable 2-max maps.
//   mpx[x,y]  = max(f[x,y], f[min(x+1,63),y])
//   mpy[x,y]  = max(f[x,y], f[x,min(y+1,63)])
//   mpxy[x,y] = 2x2 max
// One wave per pixel (4096 waves), 4 coalesced 1KB loads + 3 stores each.
// Streaming + massive TLP -> latency fully hidden (~2.5 us for ~30 MB).
// This cuts the gather's per-bin lookups from l to ~l/2 per dim, halving
// the bytes through the latency-limited miss path.
// ---------------------------------------------------------------------------
__global__ __launch_bounds__(256) void build_maps_kernel(
        const float4* __restrict__ f4,   // (FH, FW, FC/4)
        float4* __restrict__ ws)         // 3 maps, each MAPF4 float4s
{
    const int lane = threadIdx.x & 63;
    const int pix = (blockIdx.x * blockDim.x + threadIdx.x) >> 6;  // 0..4095
    const int x = pix >> 6;
    const int y = pix & 63;

    const int i00 = (x * FW + y) * (FC / 4) + lane;
    const int xn = x < FH - 1 ? x + 1 : x;
    const int yn = y < FW - 1 ? y + 1 : y;

    float4 f00 = f4[i00];
    float4 f10 = f4[(xn * FW + y) * (FC / 4) + lane];
    float4 f01 = f4[(x * FW + yn) * (FC / 4) + lane];
    float4 f11 = f4[(xn * FW + yn) * (FC / 4) + lane];

    float4 vx = fmax4(f00, f10);
    float4 vy = fmax4(f00, f01);
    float4 vxy = fmax4(vx, fmax4(f01, f11));

    ws[i00] = vx;                    // mpx
    ws[MAPF4 + i00] = vy;            // mpy
    ws[2 * MAPF4 + i00] = vxy;       // mpxy
}

// Positions covering [s, s+l) with blocks of size 2 (l>=2) or the single
// pixel (l<=1). l=1/2 -> {s}; l=3 -> {s,s+1}; l=4 -> {s,s+2}; l=5 -> {s,s+2,s+3}.
__device__ __forceinline__ int make_pos(int s, int l, int* pos) {
    if (l <= 2) { pos[0] = s; return 1; }
    int cnt = 0;
    const int last = s + l - 2;
    int p = s;
#pragma unroll 4
    while (p < last) { pos[cnt++] = p; p += 2; }
    pos[cnt++] = last;
    return cnt;
}

template <int CHK>
__device__ __forceinline__ float4 batch_max(const float4* __restrict__ base,
                                            const int* off, float4 acc) {
    float4 v[CHK];
#pragma unroll
    for (int u = 0; u < CHK; ++u) v[u] = base[off[u]];
#pragma unroll
    for (int u = 0; u < CHK; ++u) acc = fmax4(acc, v[u]);
    return acc;
}

// ---------------------------------------------------------------------------
// Gather pass: one wave per output cell, but sourcing from the premax map
// matching (bx,by) = (xlen>=2, ylen>=2), so a cell needs ~nx*ny ~= 2-4
// 1KB loads instead of xlen*ylen (~9). All control state wave-uniform.
// Input domain (0<=x1<x2<=1) makes reference clip() a no-op; positions
// p <= s+l-2 <= 62 keep the 2-blocks in range.
// ---------------------------------------------------------------------------
__global__ __launch_bounds__(256) void roi_pool_premax_kernel(
        const float4* __restrict__ f4,    // (FH, FW, FC/4)
        const float4* __restrict__ ws,    // mpx | mpy | mpxy
        const float* __restrict__ rois,   // (NROI, 4)
        float* __restrict__ out)          // (NROI, PP, PP, FC)
{
    const int lane = threadIdx.x & 63;
    int cell = (blockIdx.x * blockDim.x + threadIdx.x) >> 6;
    cell = __builtin_amdgcn_readfirstlane(cell);

    const int j = cell % PP;
    const int t = cell / PP;
    const int i = t % PP;
    const int r = t / PP;

    const float4 roi = ((const float4*)rois)[r];

    int xlo = (int)floorf(roi.x * (float)FH);
    int xspan = (int)ceilf(roi.z * (float)FH) - xlo;
    xspan = xspan > 1 ? xspan : 1;
    int ylo = (int)floorf(roi.y * (float)FW);
    int yspan = (int)ceilf(roi.w * (float)FW) - ylo;
    yspan = yspan > 1 ? yspan : 1;

    const int xs = xlo + (i * xspan) / PP;
    int xlen = (xlo + ((i + 1) * xspan + (PP - 1)) / PP) - xs;
    xlen = xlen > 1 ? xlen : 1;
    const int ys = ylo + (j * yspan) / PP;
    int ylen = (ylo + ((j + 1) * yspan + (PP - 1)) / PP) - ys;
    ylen = ylen > 1 ? ylen : 1;

    int xpos[8], ypos[8];
    const int nx = make_pos(xs, xlen, xpos);
    const int ny = make_pos(ys, ylen, ypos);

    // select source map by block sizes used in each dim
    const float4* base;
    if (xlen >= 2) base = (ylen >= 2) ? (ws + 2 * MAPF4) : ws;        // mpxy/mpx
    else           base = (ylen >= 2) ? (ws + MAPF4)     : f4;        // mpy /f
    base += lane;

    int off[9];
    int cnt = 0;
#pragma unroll 3
    for (int a = 0; a < nx; ++a)
#pragma unroll 3
        for (int b = 0; b < ny; ++b)
            off[cnt++] = (xpos[a] * FW + ypos[b]) * (FC / 4);
    const int n = cnt;
#pragma unroll
    for (int c = 0; c < 9; ++c) if (c >= n) off[c] = off[0];  // dup tail

    float4 acc = make_float4(-INFINITY, -INFINITY, -INFINITY, -INFINITY);
    if (n <= 2)      acc = batch_max<2>(base, off, acc);
    else if (n <= 4) acc = batch_max<4>(base, off, acc);
    else if (n <= 6) acc = batch_max<6>(base, off, acc);
    else             acc = batch_max<9>(base, off, acc);

    ((float4*)out)[(size_t)cell * (FC / 4) + lane] = acc;
}

// ---------------------------------------------------------------------------
// Fallback (R5 structure): direct gather, used only if ws is too small.
// ---------------------------------------------------------------------------
__global__ __launch_bounds__(256, 2) void roi_pool_direct_kernel(
        const float* __restrict__ feat, const float* __restrict__ rois,
        float* __restrict__ out)
{
    const int lane = threadIdx.x & 63;
    int cell = (blockIdx.x * blockDim.x + threadIdx.x) >> 6;
    cell = __builtin_amdgcn_readfirstlane(cell);
    const int j = cell % PP;
    const int t = cell / PP;
    const int i = t % PP;
    const int r = t / PP;
    const float4 roi = ((const float4*)rois)[r];
    int xlo = (int)floorf(roi.x * (float)FH);
    int xspan = (int)ceilf(roi.z * (float)FH) - xlo;
    xspan = xspan > 1 ? xspan : 1;
    int ylo = (int)floorf(roi.y * (float)FW);
    int yspan = (int)ceilf(roi.w * (float)FW) - ylo;
    yspan = yspan > 1 ? yspan : 1;
    const int xs = xlo + (i * xspan) / PP;
    int xlen = (xlo + ((i + 1) * xspan + (PP - 1)) / PP) - xs;
    xlen = xlen > 1 ? xlen : 1;
    const int ys = ylo + (j * yspan) / PP;
    int ylen = (ylo + ((j + 1) * yspan + (PP - 1)) / PP) - ys;
    ylen = ylen > 1 ? ylen : 1;
    const float4* __restrict__ p =
        (const float4*)feat + (size_t)(xs * FW + ys) * (FC / 4) + lane;
    const int dnext = (FC / 4);
    const int dwrap = (FW - ylen + 1) * (FC / 4);
    float4 acc = make_float4(-INFINITY, -INFINITY, -INFINITY, -INFINITY);
    const int n = xlen * ylen;
    int cur = 0, sy = 0;
    for (int q = 0; q < n; q += CHMAX) {
        const int m = n - q;
        int off[CHMAX];
        off[0] = cur;
#pragma unroll
        for (int u = 1; u < CHMAX; ++u) {
            if (u < m) {
                int wrap = (sy + 1 == ylen);
                cur += wrap ? dwrap : dnext;
                sy = wrap ? 0 : sy + 1;
            }
            off[u] = cur;
        }
        if (m <= 4)      acc = batch_max<4>(p, off, acc);
        else if (m <= 8) acc = batch_max<8>(p, off, acc);
        else             acc = batch_max<CHMAX>(p, off, acc);
        if (q + CHMAX < n) {
            int wrap = (sy + 1 == ylen);
            cur += wrap ? dwrap : dnext;
            sy = wrap ? 0 : sy + 1;
        }
    }
    ((float4*)out)[(size_t)cell * (FC / 4) + lane] = acc;
}

extern "C" void kernel_launch(void* const* d_in, const int* in_sizes, int n_in,
                              void* d_out, int out_size, void* d_ws, size_t ws_size,
                              hipStream_t stream) {
    const float* feat = (const float*)d_in[0];   // (1,64,64,256)
    const float* rois = (const float*)d_in[1];   // (1,256,4)
    float* out = (float*)d_out;                  // (1,256,7,7,256)

    const int total_threads = NROI * PP * PP * 64;  // one wave per cell
    const int block = 256;
    const int grid = (total_threads + block - 1) / block;  // 3136 exact

    if (ws_size >= WS_NEED) {
        // build 3 premax maps (4096 waves, one per pixel)
        build_maps_kernel<<<(FH * FW * 64) / block, block, 0, stream>>>(
            (const float4*)feat, (float4*)d_ws);
        roi_pool_premax_kernel<<<grid, block, 0, stream>>>(
            (const float4*)feat, (const float4*)d_ws, rois, out);
    } else {
        roi_pool_direct_kernel<<<grid, block, 0, stream>>>(feat, rois, out);
    }
}

// Round 8
// 68.739 us; speedup vs baseline: 1.0851x; 1.0851x over previous
//
#include <hip/hip_runtime.h>
#include <math.h>

// Problem constants (from reference)
#define FH 64    // feature map H (axis indexed by x)
#define FW 64    // feature map W (axis indexed by y)
#define FC 256   // channels
#define PP 7     // pool output dim
#define NROI 256
#define CHMAX 16

#define MAPF4 (FH * FW * (FC / 4))           // 262144 float4 per map
#define WS_NEED ((size_t)3 * MAPF4 * 16)     // 12.58 MB: mpx, mpy, mpxy

__device__ __forceinline__ float4 fmax4(float4 a, float4 b) {
    return make_float4(fmaxf(a.x, b.x), fmaxf(a.y, b.y),
                       fmaxf(a.z, b.z), fmaxf(a.w, b.w));
}

// ---------------------------------------------------------------------------
// Build pass: stride-1 separable 2-max maps (streaming, latency-hidden).
//   mpx[x,y] = max(f[x,y], f[x+1,y])   mpy[x,y] = max(f[x,y], f[x,y+1])
//   mpxy     = 2x2 max
// ---------------------------------------------------------------------------
__global__ __launch_bounds__(256) void build_maps_kernel(
        const float4* __restrict__ f4,   // (FH, FW, FC/4)
        float4* __restrict__ ws)         // mpx | mpy | mpxy
{
    const int lane = threadIdx.x & 63;
    const int pix = (blockIdx.x * blockDim.x + threadIdx.x) >> 6;  // 0..4095
    const int x = pix >> 6;
    const int y = pix & 63;

    const int i00 = (x * FW + y) * (FC / 4) + lane;
    const int xn = x < FH - 1 ? x + 1 : x;
    const int yn = y < FW - 1 ? y + 1 : y;

    float4 f00 = f4[i00];
    float4 f10 = f4[(xn * FW + y) * (FC / 4) + lane];
    float4 f01 = f4[(x * FW + yn) * (FC / 4) + lane];
    float4 f11 = f4[(xn * FW + yn) * (FC / 4) + lane];

    float4 vx = fmax4(f00, f10);
    float4 vy = fmax4(f00, f01);
    float4 vxy = fmax4(vx, fmax4(f01, f11));

    ws[i00] = vx;
    ws[MAPF4 + i00] = vy;
    ws[2 * MAPF4 + i00] = vxy;
}

// Batch of CHK loads; off[] must be written with compile-time indices only
// (register-promoted — NO dynamic indexing, that spills to scratch: R7 bug).
template <int CHK>
__device__ __forceinline__ float4 batch_max(const float4* __restrict__ base,
                                            const int* off, float4 acc) {
    float4 v[CHK];
#pragma unroll
    for (int u = 0; u < CHK; ++u) v[u] = base[off[u]];
#pragma unroll
    for (int u = 0; u < CHK; ++u) acc = fmax4(acc, v[u]);
    return acc;
}

// ---------------------------------------------------------------------------
// Gather: one wave per cell. Window [xs,xs+xlen) x [ys,ys+ylen), lens in
// [1,5] (w,h <= 0.5 -> span <= 33 -> bin len <= 5). Decompose each dim into
// <=3 blocks of 2 (overlap-at-end trick): pos_k = min(s+2k, s+l-2); a dim of
// len 1 stays on the raw map in that dim. Source map picked by (xlen>1,
// ylen>1). All control state wave-uniform; all offsets named scalars ->
// constant-indexed off[] arrays -> registers, no scratch.
// ---------------------------------------------------------------------------
__global__ __launch_bounds__(256) void roi_pool_premax_kernel(
        const float4* __restrict__ f4,    // (FH, FW, FC/4)
        const float4* __restrict__ ws,    // mpx | mpy | mpxy
        const float* __restrict__ rois,   // (NROI, 4)
        float* __restrict__ out)          // (NROI, PP, PP, FC)
{
    const int lane = threadIdx.x & 63;
    int cell = (blockIdx.x * blockDim.x + threadIdx.x) >> 6;
    cell = __builtin_amdgcn_readfirstlane(cell);

    const int j = cell % PP;
    const int t = cell / PP;
    const int i = t % PP;
    const int r = t / PP;

    const float4 roi = ((const float4*)rois)[r];

    int xlo = (int)floorf(roi.x * (float)FH);
    int xspan = (int)ceilf(roi.z * (float)FH) - xlo;
    xspan = xspan > 1 ? xspan : 1;
    int ylo = (int)floorf(roi.y * (float)FW);
    int yspan = (int)ceilf(roi.w * (float)FW) - ylo;
    yspan = yspan > 1 ? yspan : 1;

    // exact reference bin math (nonneg -> int div == floor); clip() is a
    // no-op in this input domain (max coord <= 63)
    const int xs = xlo + (i * xspan) / PP;
    int xlen = (xlo + ((i + 1) * xspan + (PP - 1)) / PP) - xs;
    xlen = xlen > 1 ? xlen : 1;
    const int ys = ylo + (j * yspan) / PP;
    int ylen = (ylo + ((j + 1) * yspan + (PP - 1)) / PP) - ys;
    ylen = ylen > 1 ? ylen : 1;

    // per-dim 2-block positions (closed form, <=3 each)
    const int nx = (xlen <= 2) ? 1 : ((xlen >> 1) + (xlen & 1));  // 1,1,2,2,3
    const int ny = (ylen <= 2) ? 1 : ((ylen >> 1) + (ylen & 1));
    const int xN = xs + xlen - 2;                 // last 2-block start (l>=2)
    const int x0 = xs;
    const int x1 = (xs + 2 < xN) ? xs + 2 : xN;
    const int x2 = (xs + 4 < xN) ? xs + 4 : xN;
    const int yN = ys + ylen - 2;
    const int y0 = ys;
    const int y1 = (ys + 2 < yN) ? ys + 2 : yN;
    const int y2 = (ys + 4 < yN) ? ys + 4 : yN;

    // source map by which dims use 2-blocks
    const float4* base;
    if (xlen >= 2) base = (ylen >= 2) ? (ws + 2 * MAPF4) : ws;    // mpxy/mpx
    else           base = (ylen >= 2) ? (ws + MAPF4)     : f4;    // mpy / f
    base += lane;

    const int C4 = FC / 4;
    const int o00 = (x0 * FW + y0) * C4, o01 = (x0 * FW + y1) * C4,
              o02 = (x0 * FW + y2) * C4;
    const int o10 = (x1 * FW + y0) * C4, o11 = (x1 * FW + y1) * C4,
              o12 = (x1 * FW + y2) * C4;
    const int o20 = (x2 * FW + y0) * C4, o21 = (x2 * FW + y1) * C4,
              o22 = (x2 * FW + y2) * C4;

    float4 acc = make_float4(-INFINITY, -INFINITY, -INFINITY, -INFINITY);

    switch ((nx - 1) * 3 + (ny - 1)) {            // wave-uniform
        case 0: { int off[1] = {o00};
                  acc = batch_max<1>(base, off, acc); } break;
        case 1: { int off[2] = {o00, o01};
                  acc = batch_max<2>(base, off, acc); } break;
        case 2: { int off[3] = {o00, o01, o02};
                  acc = batch_max<3>(base, off, acc); } break;
        case 3: { int off[2] = {o00, o10};
                  acc = batch_max<2>(base, off, acc); } break;
        case 4: { int off[4] = {o00, o01, o10, o11};
                  acc = batch_max<4>(base, off, acc); } break;
        case 5: { int off[6] = {o00, o01, o02, o10, o11, o12};
                  acc = batch_max<6>(base, off, acc); } break;
        case 6: { int off[3] = {o00, o10, o20};
                  acc = batch_max<3>(base, off, acc); } break;
        case 7: { int off[6] = {o00, o01, o10, o11, o20, o21};
                  acc = batch_max<6>(base, off, acc); } break;
        default: { int off[9] = {o00, o01, o02, o10, o11, o12, o20, o21, o22};
                  acc = batch_max<9>(base, off, acc); } break;
    }

    ((float4*)out)[(size_t)cell * C4 + lane] = acc;
}

// ---------------------------------------------------------------------------
// Fallback (R5 structure): direct gather, used only if ws is too small.
// ---------------------------------------------------------------------------
__global__ __launch_bounds__(256, 2) void roi_pool_direct_kernel(
        const float* __restrict__ feat, const float* __restrict__ rois,
        float* __restrict__ out)
{
    const int lane = threadIdx.x & 63;
    int cell = (blockIdx.x * blockDim.x + threadIdx.x) >> 6;
    cell = __builtin_amdgcn_readfirstlane(cell);
    const int j = cell % PP;
    const int t = cell / PP;
    const int i = t % PP;
    const int r = t / PP;
    const float4 roi = ((const float4*)rois)[r];
    int xlo = (int)floorf(roi.x * (float)FH);
    int xspan = (int)ceilf(roi.z * (float)FH) - xlo;
    xspan = xspan > 1 ? xspan : 1;
    int ylo = (int)floorf(roi.y * (float)FW);
    int yspan = (int)ceilf(roi.w * (float)FW) - ylo;
    yspan = yspan > 1 ? yspan : 1;
    const int xs = xlo + (i * xspan) / PP;
    int xlen = (xlo + ((i + 1) * xspan + (PP - 1)) / PP) - xs;
    xlen = xlen > 1 ? xlen : 1;
    const int ys = ylo + (j * yspan) / PP;
    int ylen = (ylo + ((j + 1) * yspan + (PP - 1)) / PP) - ys;
    ylen = ylen > 1 ? ylen : 1;
    const float4* __restrict__ p =
        (const float4*)feat + (size_t)(xs * FW + ys) * (FC / 4) + lane;
    const int dnext = (FC / 4);
    const int dwrap = (FW - ylen + 1) * (FC / 4);
    float4 acc = make_float4(-INFINITY, -INFINITY, -INFINITY, -INFINITY);
    const int n = xlen * ylen;
    int cur = 0, sy = 0;
    for (int q = 0; q < n; q += CHMAX) {
        const int m = n - q;
        int off[CHMAX];
        off[0] = cur;
#pragma unroll
        for (int u = 1; u < CHMAX; ++u) {
            if (u < m) {
                int wrap = (sy + 1 == ylen);
                cur += wrap ? dwrap : dnext;
                sy = wrap ? 0 : sy + 1;
            }
            off[u] = cur;
        }
        if (m <= 4)      acc = batch_max<4>(p, off, acc);
        else if (m <= 8) acc = batch_max<8>(p, off, acc);
        else             acc = batch_max<CHMAX>(p, off, acc);
        if (q + CHMAX < n) {
            int wrap = (sy + 1 == ylen);
            cur += wrap ? dwrap : dnext;
            sy = wrap ? 0 : sy + 1;
        }
    }
    ((float4*)out)[(size_t)cell * (FC / 4) + lane] = acc;
}

extern "C" void kernel_launch(void* const* d_in, const int* in_sizes, int n_in,
                              void* d_out, int out_size, void* d_ws, size_t ws_size,
                              hipStream_t stream) {
    const float* feat = (const float*)d_in[0];   // (1,64,64,256)
    const float* rois = (const float*)d_in[1];   // (1,256,4)
    float* out = (float*)d_out;                  // (1,256,7,7,256)

    const int total_threads = NROI * PP * PP * 64;  // one wave per cell
    const int block = 256;
    const int grid = (total_threads + block - 1) / block;  // 3136 exact

    if (ws_size >= WS_NEED) {
        build_maps_kernel<<<(FH * FW * 64) / block, block, 0, stream>>>(
            (const float4*)feat, (float4*)d_ws);
        roi_pool_premax_kernel<<<grid, block, 0, stream>>>(
            (const float4*)feat, (const float4*)d_ws, rois, out);
    } else {
        roi_pool_direct_kernel<<<grid, block, 0, stream>>>(feat, rois, out);
    }
}